// Round 4
// baseline (720.257 us; speedup 1.0000x reference)
//
#include <hip/hip_runtime.h>
#include <hip/hip_bf16.h>

#define BB 32
#define SS 512
#define EE 512
#define HH 8
#define DD 64
#define NROW (BB*SS)   // 16384

typedef unsigned short ushort;
typedef unsigned int u32;
typedef short bf16x8 __attribute__((ext_vector_type(8)));
typedef ushort u16x8 __attribute__((ext_vector_type(8)));
typedef float f32x4 __attribute__((ext_vector_type(4)));

__device__ __forceinline__ float bfu2f(ushort u){ return __uint_as_float(((u32)u)<<16); }
__device__ __forceinline__ ushort f2bfu(float f){
  __hip_bfloat16 h = __float2bfloat16(f);
  return *reinterpret_cast<ushort*>(&h);
}
__device__ __forceinline__ u32 cvtpk(float lo, float hi){
  u32 r; asm("v_cvt_pk_bf16_f32 %0, %1, %2" : "=v"(r) : "v"(lo), "v"(hi)); return r;
}
__device__ __forceinline__ float waveMax(float v){
  #pragma unroll
  for (int o = 32; o > 0; o >>= 1) v = fmaxf(v, __shfl_xor(v, o));
  return v;
}
__device__ __forceinline__ float waveSum(float v){
  #pragma unroll
  for (int o = 32; o > 0; o >>= 1) v += __shfl_xor(v, o);
  return v;
}
__device__ __forceinline__ void async_cp16(const ushort* g, ushort* l){
  __builtin_amdgcn_global_load_lds(
      (const __attribute__((address_space(1))) u32*)g,
      (__attribute__((address_space(3))) u32*)l, 16, 0, 0);
}

// ---------------- fused transpose of all weights: fp32 [K][N] -> bf16 [N][K] ----------------
__global__ __launch_bounds__(256) void transpose_all(
    const float* __restrict__ W_int, const float* __restrict__ Wq,
    const float* __restrict__ Wk, const float* __restrict__ Wv,
    const float* __restrict__ Wf1, ushort* __restrict__ WtALL)
{
  __shared__ float tile[32][33];
  int z = blockIdx.z;
  const float* src; int K; size_t dsto;
  switch(z){
    case 0: src=W_int;        K=512;  dsto=0;        break;
    case 1: src=Wq;           K=512;  dsto=262144;   break;
    case 2: src=Wq+262144;    K=512;  dsto=2*262144; break;
    case 3: src=Wk;           K=512;  dsto=3*262144; break;
    case 4: src=Wv;           K=512;  dsto=4*262144; break;
    case 5: src=Wk+262144;    K=512;  dsto=5*262144; break;
    case 6: src=Wv+262144;    K=512;  dsto=6*262144; break;
    default: src=Wf1;         K=1024; dsto=7*262144; break;
  }
  if ((int)blockIdx.y*32 >= K) return;
  ushort* out = WtALL + dsto;
  int lx = threadIdx.x & 31, ly = threadIdx.x >> 5;  // 32 x 8
  int n = blockIdx.x*32 + lx;
  #pragma unroll
  for (int r=0;r<32;r+=8){
    int k = blockIdx.y*32 + ly + r;
    tile[ly+r][lx] = src[(size_t)k*512 + n];
  }
  __syncthreads();
  int kk = blockIdx.y*32 + lx;
  #pragma unroll
  for (int r=0;r<32;r+=8){
    int nn = blockIdx.x*32 + ly + r;
    out[(size_t)nn*K + kk] = f2bfu(tile[lx][ly+r]);
  }
}

// ---------------- K0: T4 = type_table @ W1, colsums of W2/W3 (fp32) ----------------
__global__ __launch_bounds__(512) void k0_pre(const float* __restrict__ type_table,
                       const float* __restrict__ W_int,
                       float* __restrict__ T4, float* __restrict__ cs2, float* __restrict__ cs3)
{
  int e = threadIdx.x;
  int blk = blockIdx.x;
  float a = 0.f;
  if (blk < 4) {
    #pragma unroll 4
    for (int k = 0; k < EE; ++k)
      a += type_table[blk*EE + k] * W_int[(size_t)(EE + k)*EE + e];
    T4[blk*EE + e] = a;
  } else if (blk == 4) {
    #pragma unroll 4
    for (int k = 0; k < EE; ++k) a += W_int[(size_t)(2*EE + k)*EE + e];
    cs2[e] = a;
  } else {
    #pragma unroll 4
    for (int k = 0; k < EE; ++k) a += W_int[(size_t)(3*EE + k)*EE + e];
    cs3[e] = a;
  }
}

// ---------------- gathers: item emb -> xemb, query emb -> OBcat[:,512:] ----------------
__global__ __launch_bounds__(256) void k_gather(
    const int* __restrict__ item, const int* __restrict__ ids,
    const float* __restrict__ ut,
    ushort* __restrict__ xemb, ushort* __restrict__ obcat)
{
  int idx = blockIdx.x*256 + threadIdx.x;   // NROW*64 total
  int row = idx >> 6, c = (idx & 63)*8;
  int s = row & (SS-1);
  const float* isrc = ut + (size_t)item[row]*EE + c;
  const float* qsrc = ut + (size_t)ids[row]*EE + c;
  u16x8 xv, qv;
  #pragma unroll
  for (int i=0;i<8;++i){
    xv[i] = (s==0) ? (ushort)0 : f2bfu(isrc[i]);
    qv[i] = f2bfu(qsrc[i]);
  }
  *(u16x8*)(xemb + (size_t)row*EE + c) = xv;
  *(u16x8*)(obcat+ (size_t)row*1024 + 512 + c) = qv;
}

// ---------------- K3: M = (1-l1)*l2*softmax(tsc) + l1*softmax(rsc) -> bf16 ----------------
__global__ __launch_bounds__(256) void k3_M(
  const float* __restrict__ rel, const float* __restrict__ ts,
  const float* __restrict__ l1p, const float* __restrict__ l2p,
  ushort* __restrict__ Mout)
{
  int w = threadIdx.x >> 6, lane = threadIdx.x & 63;
  int row = blockIdx.x*4 + w;
  int q = row & (SS-1);
  const float* tr = ts + (size_t)row*SS;
  const float* rr = rel + (size_t)row*SS;
  float tv[8], rv[8];
  float m1 = -INFINITY, m2 = -1e10f;
  #pragma unroll
  for (int j=0;j<8;++j){
    int k = lane + 64*j;
    float t = tr[k];
    tv[j] = (k <= q) ? __expf(-fabsf(t)) : -INFINITY;
    m1 = fmaxf(m1, tv[j]);
    float rvv = (k > q) ? rr[k] : 0.f;
    rv[j] = (rvv == 0.f) ? -10000.f : rvv;
    m2 = fmaxf(m2, rv[j]);
  }
  m1 = waveMax(m1); m2 = waveMax(m2);
  float s1=0.f, s2=0.f;
  float p1[8], p2[8];
  #pragma unroll
  for (int j=0;j<8;++j){
    p1[j] = __expf(tv[j]-m1); s1 += p1[j];
    p2[j] = __expf(rv[j]-m2); s2 += p2[j];
  }
  s1 = waveSum(s1); s2 = waveSum(s2);
  float l1v = l1p[0], l2v = l2p[0];
  float i1 = (1.f-l1v)*l2v/s1, i2 = l1v/s2;
  ushort* Mr = Mout + (size_t)row*SS;
  #pragma unroll
  for (int j=0;j<8;++j)
    Mr[lane+64*j] = f2bfu(p1[j]*i1 + p2[j]*i2);
}

// ---------------- MFMA GEMM: C = A[M][K](lda) @ Bt[N][K]^T, bf16 in/out ----------------
// MODE 0: C[row*ldc+col]; MODE 1: [b,h,s,d]; MODE 3: z==0 -> [b,h,s,d], z==1 -> Vt[b][e][s]
// FLAGS: 1=bias, 2=relu, 8=k1 epilogue
template<int MODE, int FLAGS>
__global__ __launch_bounds__(256) void gemm_bt(
    const ushort* __restrict__ A, int lda, size_t sA,
    const ushort* __restrict__ Bt, size_t sB,
    ushort* __restrict__ C, int ldc, size_t sC,
    const float* __restrict__ bias0, const float* __restrict__ bias1, int K,
    const int* __restrict__ typeIdx, const float* __restrict__ T4f,
    const float* __restrict__ cs2, const float* __restrict__ cs3,
    const float* __restrict__ qresp, const float* __restrict__ label)
{
  __shared__ ushort As[128*32];
  __shared__ ushort Bs[128*32];
  int t = threadIdx.x;
  int w = t >> 6, l = t & 63;
  int row0 = blockIdx.x * 128;
  int n0 = blockIdx.y * 128;
  int z = blockIdx.z;
  const ushort* Ab = A + (size_t)z*sA;
  const ushort* Bb = Bt + (size_t)z*sB;
  ushort* Cb = C + (size_t)z*sC;
  const float* bias = (z == 0) ? bias0 : bias1;

  f32x4 acc[4][4];
  f32x4 zero4 = {0.f,0.f,0.f,0.f};
  #pragma unroll
  for (int i=0;i<4;++i)
    #pragma unroll
    for (int j=0;j<4;++j) acc[i][j] = zero4;

  int wr = w >> 1, wc = w & 1;
  int lr = l & 15, lg = l >> 4;
  int arow = wr*64 + lr;
  int brow = wc*64 + lr;
  int kgrp = lg*8;

  for (int k0 = 0; k0 < K; k0 += 32) {
    #pragma unroll
    for (int j=0;j<2;++j){
      int off = (j*256 + t)*8;           // ushort offset within 128x32 tile
      int r = off >> 5, kc = off & 31;
      async_cp16(Ab + (size_t)(row0 + r)*lda + k0 + kc, As + off);
      async_cp16(Bb + (size_t)(n0  + r)*K   + k0 + kc, Bs + off);
    }
    asm volatile("s_waitcnt vmcnt(0)" ::: "memory");
    __syncthreads();
    bf16x8 af[4], bfr[4];
    #pragma unroll
    for (int i=0;i<4;++i){
      af[i]  = *(const bf16x8*)(As + (arow + i*16)*32 + kgrp);
      bfr[i] = *(const bf16x8*)(Bs + (brow + i*16)*32 + kgrp);
    }
    #pragma unroll
    for (int i=0;i<4;++i)
      #pragma unroll
      for (int j=0;j<4;++j)
        acc[i][j] = __builtin_amdgcn_mfma_f32_16x16x32_bf16(af[i], bfr[j], acc[i][j], 0,0,0);
    __syncthreads();
  }

  int crow0 = row0 + wr*64 + lg*4;
  int ccol0 = n0 + wc*64 + lr;
  #pragma unroll
  for (int mi=0;mi<4;++mi){
    #pragma unroll
    for (int ni=0;ni<4;++ni){
      int col = ccol0 + ni*16;
      float bv = 0.f;
      if constexpr ((FLAGS & 1) != 0) bv = bias[col];
      #pragma unroll
      for (int j=0;j<4;++j){
        int row = crow0 + mi*16 + j;
        float v = acc[mi][ni][j] + bv;
        if constexpr ((FLAGS & 8) != 0) {
          int tt = typeIdx[row];
          v += T4f[tt*EE + col] + qresp[row]*cs2[col] + label[row]*cs3[col];
        }
        if constexpr ((FLAGS & 2) != 0) v = fmaxf(v, 0.f);
        size_t idx;
        if constexpr (MODE == 0)      idx = (size_t)row*ldc + col;
        else if constexpr (MODE == 1) idx = ((size_t)(row>>9)*HH + (col>>6))*(SS*DD) + (size_t)(row&(SS-1))*DD + (col&63);
        else {
          if (z == 0) idx = ((size_t)(row>>9)*HH + (col>>6))*(SS*DD) + (size_t)(row&(SS-1))*DD + (col&63);
          else        idx = (size_t)(row>>9)*(EE*SS) + (size_t)col*SS + (row&(SS-1));
        }
        Cb[idx] = f2bfu(v);
      }
    }
  }
}

// ---------------- fused flash attention + M@V ----------------
// out^T[d][q] per wave via swapped mfma(K,Q); ONLINE-max softmax (round-2 numerics);
// M@V fused (full k range). qb,kb: [b,h,s,d]; vt: [b][e][s]; mbuf: [b][q][k] (all bf16)
// outp = OBcat (ld 1024), cols h*64..; RESID: out = old + relu(v), else out = v
template<int RESID>
__global__ __launch_bounds__(256) void flash_fused(
    const ushort* __restrict__ qb, const ushort* __restrict__ kb,
    const ushort* __restrict__ vt, const ushort* __restrict__ mbuf,
    const float* __restrict__ l1p, const float* __restrict__ l2p,
    ushort* __restrict__ outp)
{
  __shared__ ushort lds_o[4][16][72];
  const int bh = blockIdx.x, b = bh>>3, h = bh&7;
  const int q0 = blockIdx.y*64;
  const int t = threadIdx.x, w = t>>6, l = t&63;
  const int lr = l&15, lg = l>>4;
  const int qw = q0 + w*16;
  const float c1 = (1.f - l1p[0])*(1.f - l2p[0]);
  const int nt = ((qw+15)>>7) + 1;   // # of 128-k tiles with causal content
  const float C1 = 0.125f * 1.44269504f;  // scale * log2(e)

  // Q fragment (B-operand): Q[qw+lr][dh*32 + lg*8 + 0..7]
  const ushort* qrow = qb + ((size_t)bh*SS + qw + lr)*DD;
  bf16x8 qa0 = *(const bf16x8*)(qrow + lg*8);
  bf16x8 qa1 = *(const bf16x8*)(qrow + 32 + lg*8);

  const ushort* kbase = kb + (size_t)bh*SS*DD;
  const ushort* vbase = vt + ((size_t)b*EE + h*DD)*SS;
  const ushort* mrow  = mbuf + ((size_t)(b*SS) + qw + lr)*SS;

  // permuted K-row sub-index for this lane: 8*(lr>>2) + (lr&3)
  const int prow = ((lr>>2)<<3) | (lr&3);
  const int kmy = lg*8;   // k offset of this lane's lg group (for masking)

  f32x4 pacc[4], macc[4];
  f32x4 zero4 = {0.f,0.f,0.f,0.f};
  #pragma unroll
  for (int i=0;i<4;++i){ pacc[i]=zero4; macc[i]=zero4; }
  float li = 0.f;
  float mx = -1e30f;   // running raw-score max for q = qw+lr

  for (int kt=0; kt<4; ++kt){
    const int kv0 = kt*128;
    const bool causal = (kt < nt);
    u32 pk[8][2];
    if (causal){
      f32x4 sc[8];
      #pragma unroll
      for (int i=0;i<8;++i) sc[i]=zero4;
      #pragma unroll
      for (int ni=0; ni<8; ++ni){
        int krow = kv0 + ((ni>>1)<<5) + ((ni&1)<<2) + prow;
        const ushort* kp = kbase + (size_t)krow*DD + lg*8;
        bf16x8 kf0 = *(const bf16x8*)(kp);
        bf16x8 kf1 = *(const bf16x8*)(kp + 32);
        sc[ni] = __builtin_amdgcn_mfma_f32_16x16x32_bf16(kf0, qa0, sc[ni], 0,0,0);
        sc[ni] = __builtin_amdgcn_mfma_f32_16x16x32_bf16(kf1, qa1, sc[ni], 0,0,0);
      }
      if (kt == nt-1){         // diagonal tile: mask k > q
        int q = qw + lr;
        #pragma unroll
        for (int ni=0; ni<8; ++ni){
          int kb0 = kv0 + ((ni>>1)<<5) + ((ni&1)<<2) + kmy;
          #pragma unroll
          for (int j=0;j<4;++j)
            sc[ni][j] = (kb0 + j > q) ? -1e30f : sc[ni][j];
        }
      }
      // online max across tiles (per q-row = lane's lr; reduce over lg groups)
      float tm = -1e30f;
      #pragma unroll
      for (int ni=0; ni<8; ++ni)
        #pragma unroll
        for (int j=0;j<4;++j) tm = fmaxf(tm, sc[ni][j]);
      tm = fmaxf(tm, __shfl_xor(tm,16));
      tm = fmaxf(tm, __shfl_xor(tm,32));
      float nm = fmaxf(mx, tm);
      float corr = __builtin_exp2f((mx - nm)*C1);
      mx = nm;
      float mcc = nm * C1;
      float tsum = 0.f;
      #pragma unroll
      for (int ni=0;ni<8;++ni){
        float p0 = __builtin_exp2f(fmaf(sc[ni][0], C1, -mcc));
        float p1 = __builtin_exp2f(fmaf(sc[ni][1], C1, -mcc));
        float p2 = __builtin_exp2f(fmaf(sc[ni][2], C1, -mcc));
        float p3 = __builtin_exp2f(fmaf(sc[ni][3], C1, -mcc));
        tsum += (p0+p1)+(p2+p3);
        pk[ni][0] = cvtpk(p0,p1);
        pk[ni][1] = cvtpk(p2,p3);
      }
      li = li*corr + tsum;
      #pragma unroll
      for (int i=0;i<4;++i) pacc[i] *= corr;   // rescale softmax-PV accumulator ONLY
    }
    #pragma unroll
    for (int kh=0; kh<4; ++kh){
      bf16x8 ma = *(const bf16x8*)(mrow + kv0 + kh*32 + lg*8);
      bf16x8 pa;
      if (causal){
        union { u32 u[4]; bf16x8 v; } pu;
        pu.u[0]=pk[2*kh][0]; pu.u[1]=pk[2*kh][1];
        pu.u[2]=pk[2*kh+1][0]; pu.u[3]=pk[2*kh+1][1];
        pa = pu.v;
      }
      #pragma unroll
      for (int ni2=0; ni2<4; ++ni2){
        bf16x8 vf = *(const bf16x8*)(vbase + (size_t)(ni2*16 + lr)*SS + kv0 + kh*32 + lg*8);
        macc[ni2] = __builtin_amdgcn_mfma_f32_16x16x32_bf16(vf, ma, macc[ni2], 0,0,0);
        if (causal)
          pacc[ni2] = __builtin_amdgcn_mfma_f32_16x16x32_bf16(vf, pa, pacc[ni2], 0,0,0);
      }
    }
  }
  li += __shfl_xor(li,16);
  li += __shfl_xor(li,32);
  float rinv = c1 / li;

  // stage out^T -> LDS (per-wave), then coalesced global write
  #pragma unroll
  for (int ni2=0; ni2<4; ++ni2){
    #pragma unroll
    for (int jh=0; jh<2; ++jh){
      float v0 = fmaf(pacc[ni2][2*jh+0], rinv, macc[ni2][2*jh+0]);
      float v1 = fmaf(pacc[ni2][2*jh+1], rinv, macc[ni2][2*jh+1]);
      *(u32*)&lds_o[w][lr][ni2*16 + lg*4 + 2*jh] = cvtpk(v0, v1);
    }
  }
  __syncthreads();
  int rr = l>>2, cc = (l&3)*16;
  u16x8 o0 = *(u16x8*)&lds_o[w][rr][cc];
  u16x8 o1 = *(u16x8*)&lds_o[w][rr][cc+8];
  size_t gaddr = ((size_t)(b*SS) + qw + rr)*1024 + h*DD + cc;
  if constexpr (RESID){
    u16x8 old0 = *(const u16x8*)(outp + gaddr);
    u16x8 old1 = *(const u16x8*)(outp + gaddr + 8);
    #pragma unroll
    for (int i=0;i<8;++i){
      o0[i] = f2bfu(bfu2f(old0[i]) + fmaxf(bfu2f(o0[i]), 0.f));
      o1[i] = f2bfu(bfu2f(old1[i]) + fmaxf(bfu2f(o1[i]), 0.f));
    }
  }
  *(u16x8*)(outp + gaddr) = o0;
  *(u16x8*)(outp + gaddr + 8) = o1;
}

// ---------------- out = h @ Wf2 + bf2 ----------------
__global__ __launch_bounds__(256) void k_ffn2(
    const ushort* __restrict__ hB, const float* __restrict__ Wf2,
    const float* __restrict__ bf2p, float* __restrict__ outp)
{
  int w = threadIdx.x >> 6, l = threadIdx.x & 63;
  int row = blockIdx.x*4 + w;
  bf16x8 hv = *(const bf16x8*)(hB + (size_t)row*EE + l*8);
  float s = 0.f;
  #pragma unroll
  for (int i=0;i<8;++i) s += bfu2f((ushort)hv[i]) * Wf2[l*8+i];
  s = waveSum(s);
  if (l == 0) outp[row] = s + bf2p[0];
}

extern "C" void kernel_launch(void* const* d_in, const int* in_sizes, int n_in,
                              void* d_out, int out_size, void* d_ws, size_t ws_size,
                              hipStream_t stream)
{
  const int*   item_inputs = (const int*)d_in[0];
  const float* label_in    = (const float*)d_in[1];
  const int*   type_inputs = (const int*)d_in[2];
  const int*   item_ids    = (const int*)d_in[3];
  const float* rel         = (const float*)d_in[4];
  const float* tstamp      = (const float*)d_in[5];
  const float* qresp       = (const float*)d_in[6];
  const float* use_table   = (const float*)d_in[7];
  const float* type_table  = (const float*)d_in[8];
  const float* W_int       = (const float*)d_in[9];
  const float* b_int       = (const float*)d_in[10];
  const float* Wq          = (const float*)d_in[11];
  const float* bq          = (const float*)d_in[12];
  const float* Wk          = (const float*)d_in[13];
  const float* bk          = (const float*)d_in[14];
  const float* Wv          = (const float*)d_in[15];
  const float* bv          = (const float*)d_in[16];
  const float* Wf1         = (const float*)d_in[17];
  const float* bf1         = (const float*)d_in[18];
  const float* Wf2         = (const float*)d_in[19];
  const float* bf2         = (const float*)d_in[20];
  const float* l1p         = (const float*)d_in[21];
  const float* l2p         = (const float*)d_in[22];
  float* out = (float*)d_out;
  (void)in_sizes; (void)n_in; (void)out_size; (void)ws_size;

  char* p = (char*)d_ws;
  auto alloc = [&](size_t bytes)->char*{ char* r = p; p += (bytes + 255) & ~(size_t)255; return r; };
  const size_t NE  = (size_t)NROW*EE;
  const size_t NE2 = NE*2;
  ushort* xemb    = (ushort*)alloc(NE2);
  ushort* inputsB = (ushort*)alloc(NE2);
  ushort* Mbuf    = (ushort*)alloc((size_t)BB*SS*SS*2);
  ushort* qB2     = (ushort*)alloc(2*NE2);
  ushort* kvB     = (ushort*)alloc(2*NE2);          // kB | VtB adjacent
  ushort* OBcat   = (ushort*)alloc((size_t)NROW*1024*2);
  ushort* hB      = (ushort*)alloc(NE2);
  ushort* WtALL   = (ushort*)alloc((size_t)(7*262144 + 524288)*2);
  float*  T4f     = (float*)alloc(4*EE*4);
  float*  cs2     = (float*)alloc(EE*4);
  float*  cs3     = (float*)alloc(EE*4);
  ushort* kB  = kvB;
  ushort* VtB = kvB + NE;

  const int* nullI = nullptr;
  const float* nullF = nullptr;

  // prep
  transpose_all<<<dim3(16,32,8),256,0,stream>>>(W_int, Wq, Wk, Wv, Wf1, WtALL);
  k0_pre<<<6,512,0,stream>>>(type_table, W_int, T4f, cs2, cs3);
  k_gather<<<NROW/4,256,0,stream>>>(item_inputs, item_ids, use_table, xemb, OBcat);
  k3_M<<<NROW/4,256,0,stream>>>(rel, tstamp, l1p, l2p, Mbuf);

  // inputs = relu(item@W0 + T4[type] + qresp*cs2 + label*cs3 + b_int)
  gemm_bt<0,11><<<dim3(128,4,1),256,0,stream>>>(xemb,512,0, WtALL,0, inputsB,512,0,
                                                b_int, nullF, 512,
                                                type_inputs, T4f, cs2, cs3, qresp, label_in);
  // Q projections, both layers (A = OBcat[:,512:])
  gemm_bt<1,1><<<dim3(128,4,2),256,0,stream>>>(OBcat+512,1024,0, WtALL+262144,262144,
                                               qB2,0,NE, bq, bq+EE, 512,
                                               nullI,nullF,nullF,nullF,nullF,nullF);
  // layer 0 K,V
  gemm_bt<3,1><<<dim3(128,4,2),256,0,stream>>>(inputsB,512,0, WtALL+3*262144,262144,
                                               kB,0,NE, bk, bv, 512,
                                               nullI,nullF,nullF,nullF,nullF,nullF);
  flash_fused<0><<<dim3(BB*HH, SS/64),256,0,stream>>>(qB2, kB, VtB, Mbuf, l1p, l2p, OBcat);
  // layer 1 K,V (from OBcat[:, :512])
  gemm_bt<3,1><<<dim3(128,4,2),256,0,stream>>>(OBcat,1024,0, WtALL+5*262144,262144,
                                               kB,0,NE, bk+EE, bv+EE, 512,
                                               nullI,nullF,nullF,nullF,nullF,nullF);
  flash_fused<1><<<dim3(BB*HH, SS/64),256,0,stream>>>(qB2+NE, kB, VtB, Mbuf, l1p, l2p, OBcat);
  // final MLP
  gemm_bt<0,3><<<dim3(128,4,1),256,0,stream>>>(OBcat,1024,0, WtALL+7*262144,0, hB,512,0,
                                               bf1, nullF, 1024,
                                               nullI,nullF,nullF,nullF,nullF,nullF);
  k_ffn2<<<NROW/4,256,0,stream>>>(hB, Wf2, bf2, out);
}

// Round 5
// 652.110 us; speedup vs baseline: 1.1045x; 1.1045x over previous
//
#include <hip/hip_runtime.h>
#include <hip/hip_bf16.h>

#define BB 32
#define SS 512
#define EE 512
#define HH 8
#define DD 64
#define NROW (BB*SS)   // 16384

typedef unsigned short ushort;
typedef unsigned int u32;
typedef short bf16x8 __attribute__((ext_vector_type(8)));
typedef ushort u16x8 __attribute__((ext_vector_type(8)));
typedef float f32x4 __attribute__((ext_vector_type(4)));

__device__ __forceinline__ float bfu2f(ushort u){ return __uint_as_float(((u32)u)<<16); }
__device__ __forceinline__ ushort f2bfu(float f){
  __hip_bfloat16 h = __float2bfloat16(f);
  return *reinterpret_cast<ushort*>(&h);
}
__device__ __forceinline__ u32 cvtpk(float lo, float hi){
  u32 r; asm("v_cvt_pk_bf16_f32 %0, %1, %2" : "=v"(r) : "v"(lo), "v"(hi)); return r;
}
__device__ __forceinline__ float waveMax(float v){
  #pragma unroll
  for (int o = 32; o > 0; o >>= 1) v = fmaxf(v, __shfl_xor(v, o));
  return v;
}
__device__ __forceinline__ float waveSum(float v){
  #pragma unroll
  for (int o = 32; o > 0; o >>= 1) v += __shfl_xor(v, o);
  return v;
}
__device__ __forceinline__ void async_cp16(const ushort* g, ushort* l){
  __builtin_amdgcn_global_load_lds(
      (const __attribute__((address_space(1))) u32*)g,
      (__attribute__((address_space(3))) u32*)l, 16, 0, 0);
}

// ---------------- fused transpose of all weights: fp32 [K][N] -> bf16 [N][K] ----------------
__global__ __launch_bounds__(256) void transpose_all(
    const float* __restrict__ W_int, const float* __restrict__ Wq,
    const float* __restrict__ Wk, const float* __restrict__ Wv,
    const float* __restrict__ Wf1, ushort* __restrict__ WtALL)
{
  __shared__ float tile[32][33];
  int z = blockIdx.z;
  const float* src; int K; size_t dsto;
  switch(z){
    case 0: src=W_int;        K=512;  dsto=0;        break;
    case 1: src=Wq;           K=512;  dsto=262144;   break;
    case 2: src=Wq+262144;    K=512;  dsto=2*262144; break;
    case 3: src=Wk;           K=512;  dsto=3*262144; break;
    case 4: src=Wv;           K=512;  dsto=4*262144; break;
    case 5: src=Wk+262144;    K=512;  dsto=5*262144; break;
    case 6: src=Wv+262144;    K=512;  dsto=6*262144; break;
    default: src=Wf1;         K=1024; dsto=7*262144; break;
  }
  if ((int)blockIdx.y*32 >= K) return;
  ushort* out = WtALL + dsto;
  int lx = threadIdx.x & 31, ly = threadIdx.x >> 5;  // 32 x 8
  int n = blockIdx.x*32 + lx;
  #pragma unroll
  for (int r=0;r<32;r+=8){
    int k = blockIdx.y*32 + ly + r;
    tile[ly+r][lx] = src[(size_t)k*512 + n];
  }
  __syncthreads();
  int kk = blockIdx.y*32 + lx;
  #pragma unroll
  for (int r=0;r<32;r+=8){
    int nn = blockIdx.x*32 + ly + r;
    out[(size_t)nn*K + kk] = f2bfu(tile[lx][ly+r]);
  }
}

// ---------------- K0: zero then atomic partial-K accumulate ----------------
__global__ __launch_bounds__(512) void k0_zero(float* __restrict__ T4f){
  int i = blockIdx.x*512 + threadIdx.x;
  T4f[i] = 0.f;      // grid 6, covers 6*512 floats (T4 | cs2 | cs3)
}
__global__ __launch_bounds__(512) void k0_pre(const float* __restrict__ type_table,
                       const float* __restrict__ W_int, float* __restrict__ T4f)
{
  int e = threadIdx.x;
  int blk = blockIdx.x;          // 0..5
  int k0 = blockIdx.y * 64;      // 8 K-chunks
  float a = 0.f;
  if (blk < 4) {
    #pragma unroll 4
    for (int k = k0; k < k0+64; ++k)
      a += type_table[blk*EE + k] * W_int[(size_t)(EE + k)*EE + e];
  } else if (blk == 4) {
    #pragma unroll 4
    for (int k = k0; k < k0+64; ++k) a += W_int[(size_t)(2*EE + k)*EE + e];
  } else {
    #pragma unroll 4
    for (int k = k0; k < k0+64; ++k) a += W_int[(size_t)(3*EE + k)*EE + e];
  }
  atomicAdd(&T4f[blk*EE + e], a);
}

// ---------------- gathers: item emb -> xemb, query emb -> OBcat[:,512:] ----------------
__global__ __launch_bounds__(256) void k_gather(
    const int* __restrict__ item, const int* __restrict__ ids,
    const float* __restrict__ ut,
    ushort* __restrict__ xemb, ushort* __restrict__ obcat)
{
  int idx = blockIdx.x*256 + threadIdx.x;   // NROW*64 total
  int row = idx >> 6, c = (idx & 63)*8;
  int s = row & (SS-1);
  const float* isrc = ut + (size_t)item[row]*EE + c;
  const float* qsrc = ut + (size_t)ids[row]*EE + c;
  u16x8 xv, qv;
  #pragma unroll
  for (int i=0;i<8;++i){
    xv[i] = (s==0) ? (ushort)0 : f2bfu(isrc[i]);
    qv[i] = f2bfu(qsrc[i]);
  }
  *(u16x8*)(xemb + (size_t)row*EE + c) = xv;
  *(u16x8*)(obcat+ (size_t)row*1024 + 512 + c) = qv;
}

// ---------------- K3: M = (1-l1)*l2*softmax(tsc) + l1*softmax(rsc) -> bf16 ----------------
__global__ __launch_bounds__(256) void k3_M(
  const float* __restrict__ rel, const float* __restrict__ ts,
  const float* __restrict__ l1p, const float* __restrict__ l2p,
  ushort* __restrict__ Mout)
{
  int w = threadIdx.x >> 6, lane = threadIdx.x & 63;
  int row = blockIdx.x*4 + w;
  int q = row & (SS-1);
  const float* tr = ts + (size_t)row*SS;
  const float* rr = rel + (size_t)row*SS;
  float tv[8], rv[8];
  float m1 = -INFINITY, m2 = -1e10f;
  #pragma unroll
  for (int j=0;j<8;++j){
    int k = lane + 64*j;
    float t = tr[k];
    tv[j] = (k <= q) ? __expf(-fabsf(t)) : -INFINITY;
    m1 = fmaxf(m1, tv[j]);
    float rvv = (k > q) ? rr[k] : 0.f;
    rv[j] = (rvv == 0.f) ? -10000.f : rvv;
    m2 = fmaxf(m2, rv[j]);
  }
  m1 = waveMax(m1); m2 = waveMax(m2);
  float s1=0.f, s2=0.f;
  float p1[8], p2[8];
  #pragma unroll
  for (int j=0;j<8;++j){
    p1[j] = __expf(tv[j]-m1); s1 += p1[j];
    p2[j] = __expf(rv[j]-m2); s2 += p2[j];
  }
  s1 = waveSum(s1); s2 = waveSum(s2);
  float l1v = l1p[0], l2v = l2p[0];
  float i1 = (1.f-l1v)*l2v/s1, i2 = l1v/s2;
  ushort* Mr = Mout + (size_t)row*SS;
  #pragma unroll
  for (int j=0;j<8;++j)
    Mr[lane+64*j] = f2bfu(p1[j]*i1 + p2[j]*i2);
}

// ---------------- MFMA GEMM, 2-phase dbuf pipeline ----------------
// MODE 0: C[row*ldc+col]; MODE 1: [b,h,s,d]; MODE 3: z==0 -> [b,h,s,d], z==1 -> Vt[b][e][s]
// FLAGS: 1=bias, 2=relu, 8=k1 epilogue, 16=f32-out, 32=MV compose (C=v+RB), 64=MV compose+relu-add
// GRID: 0 = (x,y,z) grid; 1 = flat XCD-swizzled (512 blocks, 4x4 tiles x 32 batches)
template<int MODE, int FLAGS, int GRID>
__global__ __launch_bounds__(256) void gemm_bt(
    const ushort* __restrict__ A, int lda, size_t sA,
    const ushort* __restrict__ Bt, size_t sB,
    ushort* __restrict__ C, int ldc, size_t sC,
    const ushort* __restrict__ RBp,
    const float* __restrict__ bias0, const float* __restrict__ bias1, int K,
    const int* __restrict__ typeIdx, const float* __restrict__ T4f,
    const float* __restrict__ cs2, const float* __restrict__ cs3,
    const float* __restrict__ qresp, const float* __restrict__ label)
{
  __shared__ ushort As[2][128*32];
  __shared__ ushort Bs[2][128*32];
  int bx, by, z;
  if constexpr (GRID == 0){ bx = blockIdx.x; by = blockIdx.y; z = blockIdx.z; }
  else {
    int wg = blockIdx.x;
    int xcd = wg & 7, t2 = wg >> 3;
    z = (xcd << 2) | (t2 >> 4);        // 4 batches per XCD -> M[b],Vt[b] L2-resident
    int tile = t2 & 15;
    bx = tile & 3; by = tile >> 2;
  }
  int t = threadIdx.x;
  int w = t >> 6, l = t & 63;
  int row0 = bx * 128;
  int n0 = by * 128;
  const ushort* Ab = A + (size_t)z*sA;
  const ushort* Bb = Bt + (size_t)z*sB;
  ushort* Cb = C + (size_t)z*sC;
  const float* bias = (z == 0) ? bias0 : bias1;

  f32x4 acc[4][4];
  f32x4 zero4 = {0.f,0.f,0.f,0.f};
  #pragma unroll
  for (int i=0;i<4;++i)
    #pragma unroll
    for (int j=0;j<4;++j) acc[i][j] = zero4;

  int wr = w >> 1, wc = w & 1;
  int lr = l & 15, lg = l >> 4;
  int arow = wr*64 + lr;
  int brow = wc*64 + lr;
  int kgrp = lg*8;

  auto STAGE = [&](int buf, int k0){
    #pragma unroll
    for (int j=0;j<2;++j){
      int off = (j*256 + t)*8;           // ushort offset within 128x32 tile
      int r = off >> 5, kc = off & 31;
      async_cp16(Ab + (size_t)(row0 + r)*lda + k0 + kc, &As[buf][off]);
      async_cp16(Bb + (size_t)(n0  + r)*K   + k0 + kc, &Bs[buf][off]);
    }
  };

  STAGE(0, 0);
  asm volatile("s_waitcnt vmcnt(0)" ::: "memory");
  __syncthreads();
  int cur = 0;
  for (int k0 = 0; k0 < K; k0 += 32) {
    if (k0 + 32 < K) STAGE(cur^1, k0+32);   // prefetch overlaps MFMA below
    bf16x8 af[4], bfr[4];
    #pragma unroll
    for (int i=0;i<4;++i){
      af[i]  = *(const bf16x8*)(&As[cur][(arow + i*16)*32 + kgrp]);
      bfr[i] = *(const bf16x8*)(&Bs[cur][(brow + i*16)*32 + kgrp]);
    }
    #pragma unroll
    for (int i=0;i<4;++i)
      #pragma unroll
      for (int j=0;j<4;++j)
        acc[i][j] = __builtin_amdgcn_mfma_f32_16x16x32_bf16(af[i], bfr[j], acc[i][j], 0,0,0);
    asm volatile("s_waitcnt vmcnt(0)" ::: "memory");
    __syncthreads();
    cur ^= 1;
  }

  int crow0 = row0 + wr*64 + lg*4;
  int ccol0 = n0 + wc*64 + lr;
  #pragma unroll
  for (int mi=0;mi<4;++mi){
    #pragma unroll
    for (int ni=0;ni<4;++ni){
      int col = ccol0 + ni*16;
      float bv = 0.f;
      if constexpr ((FLAGS & 1) != 0) bv = bias[col];
      #pragma unroll
      for (int j=0;j<4;++j){
        int row = crow0 + mi*16 + j;
        float v = acc[mi][ni][j] + bv;
        if constexpr ((FLAGS & 8) != 0) {
          int tt = typeIdx[row];
          v += T4f[tt*EE + col] + qresp[row]*cs2[col] + label[row]*cs3[col];
        }
        if constexpr ((FLAGS & 2) != 0) v = fmaxf(v, 0.f);
        if constexpr ((FLAGS & (32|64)) != 0)
          v += bfu2f(RBp[(size_t)z*262144 + row*512 + col]);   // + flash output
        size_t idx;
        if constexpr (MODE == 0)      idx = (size_t)row*ldc + col;
        else if constexpr (MODE == 1) idx = ((size_t)(row>>9)*HH + (col>>6))*(SS*DD) + (size_t)(row&(SS-1))*DD + (col&63);
        else {
          if (z == 0) idx = ((size_t)(row>>9)*HH + (col>>6))*(SS*DD) + (size_t)(row&(SS-1))*DD + (col&63);
          else        idx = (size_t)(row>>9)*(EE*SS) + (size_t)col*SS + (row&(SS-1));
        }
        if constexpr ((FLAGS & 16) != 0) ((float*)Cb)[idx] = v;
        else if constexpr ((FLAGS & 64) != 0) {
          float old = bfu2f(Cb[idx]);
          Cb[idx] = f2bfu(old + fmaxf(v, 0.f));
        } else Cb[idx] = f2bfu(v);
      }
    }
  }
}

// ---------------- flash attention (softmax part only): out = c1*softmax(QK^T/8)@V ----
// swapped mfma(K,Q), register P, online max; causal tiles only; XCD-swizzled grid.
// qb,kb: [b,h,s,d]; vt: [b][e][s]; outp: RB row-major ld 512
__global__ __launch_bounds__(256) void flash_attn(
    const ushort* __restrict__ qb, const ushort* __restrict__ kb,
    const ushort* __restrict__ vt,
    const float* __restrict__ l1p, const float* __restrict__ l2p,
    ushort* __restrict__ outp)
{
  __shared__ ushort lds_o[4][16][72];
  int wg = blockIdx.x;                 // 2048 blocks
  int xcd = wg & 7, tt = wg >> 3;
  int bh = (xcd << 5) | (tt >> 3);     // 32 heads per XCD -> K/V L2-resident
  int q0 = (tt & 7) * 64;
  const int b = bh>>3, h = bh&7;
  const int t = threadIdx.x, w = t>>6, l = t&63;
  const int lr = l&15, lg = l>>4;
  const int qw = q0 + w*16;
  const float c1 = (1.f - l1p[0])*(1.f - l2p[0]);
  const int nt = ((qw+15)>>7) + 1;     // # of 128-k tiles with causal content
  const float C1 = 0.125f * 1.44269504f;

  const ushort* qrow = qb + ((size_t)bh*SS + qw + lr)*DD;
  bf16x8 qa0 = *(const bf16x8*)(qrow + lg*8);
  bf16x8 qa1 = *(const bf16x8*)(qrow + 32 + lg*8);

  const char* kbaseC = (const char*)(kb + (size_t)bh*SS*DD);
  const char* vbaseC = (const char*)(vt + ((size_t)b*EE + h*DD)*SS);
  const int prow = ((lr>>2)<<3) | (lr&3);          // permuted K-row sub-index
  const u32 klane = (u32)(prow*128 + lg*16);       // bytes
  const u32 vlane = (u32)(lr*1024 + lg*16);        // bytes

  f32x4 pacc[4];
  f32x4 zero4 = {0.f,0.f,0.f,0.f};
  #pragma unroll
  for (int i=0;i<4;++i) pacc[i]=zero4;
  float li = 0.f;
  float mx = -1e30f;

  for (int kt=0; kt<nt; ++kt){
    const int kv0 = kt*128;
    const u32 kbase_t = klane + (u32)kt*16384u;
    f32x4 sc[8];
    #pragma unroll
    for (int i=0;i<8;++i) sc[i]=zero4;
    #pragma unroll
    for (int ni=0; ni<8; ++ni){
      const char* kp = kbaseC + (kbase_t + (ni>>1)*4096u + (ni&1)*512u);
      bf16x8 kf0 = *(const bf16x8*)(kp);
      bf16x8 kf1 = *(const bf16x8*)(kp + 64);
      sc[ni] = __builtin_amdgcn_mfma_f32_16x16x32_bf16(kf0, qa0, sc[ni], 0,0,0);
      sc[ni] = __builtin_amdgcn_mfma_f32_16x16x32_bf16(kf1, qa1, sc[ni], 0,0,0);
    }
    if (kt == nt-1){                   // diagonal tile: mask k > q
      int q = qw + lr;
      #pragma unroll
      for (int ni=0; ni<8; ++ni){
        int kb0 = kv0 + ((ni>>1)<<5) + ((ni&1)<<2) + lg*8;
        #pragma unroll
        for (int j=0;j<4;++j)
          sc[ni][j] = (kb0 + j > q) ? -1e30f : sc[ni][j];
      }
    }
    // online max (per q-row: this lane's lr; reduce over lg groups)
    float tm = -1e30f;
    #pragma unroll
    for (int ni=0; ni<8; ++ni)
      #pragma unroll
      for (int j=0;j<4;++j) tm = fmaxf(tm, sc[ni][j]);
    tm = fmaxf(tm, __shfl_xor(tm,16));
    tm = fmaxf(tm, __shfl_xor(tm,32));
    float nm = fmaxf(mx, tm);
    float corr = __builtin_exp2f((mx - nm)*C1);
    mx = nm;
    float mcc = nm * C1;
    float tsum = 0.f;
    u32 pk[8][2];
    #pragma unroll
    for (int ni=0;ni<8;++ni){
      float p0 = __builtin_exp2f(fmaf(sc[ni][0], C1, -mcc));
      float p1 = __builtin_exp2f(fmaf(sc[ni][1], C1, -mcc));
      float p2 = __builtin_exp2f(fmaf(sc[ni][2], C1, -mcc));
      float p3 = __builtin_exp2f(fmaf(sc[ni][3], C1, -mcc));
      tsum += (p0+p1)+(p2+p3);
      pk[ni][0] = cvtpk(p0,p1);
      pk[ni][1] = cvtpk(p2,p3);
    }
    li = li*corr + tsum;
    #pragma unroll
    for (int i=0;i<4;++i) pacc[i] *= corr;
    // PV
    #pragma unroll
    for (int kh=0; kh<4; ++kh){
      union { u32 u[4]; bf16x8 v; } pu;
      pu.u[0]=pk[2*kh][0]; pu.u[1]=pk[2*kh][1];
      pu.u[2]=pk[2*kh+1][0]; pu.u[3]=pk[2*kh+1][1];
      bf16x8 pa = pu.v;
      const u32 vbase_t = vlane + (u32)(kv0*2 + kh*64);
      #pragma unroll
      for (int ni2=0; ni2<4; ++ni2){
        bf16x8 vf = *(const bf16x8*)(vbaseC + (vbase_t + ni2*16384u));
        pacc[ni2] = __builtin_amdgcn_mfma_f32_16x16x32_bf16(vf, pa, pacc[ni2], 0,0,0);
      }
    }
  }
  li += __shfl_xor(li,16);
  li += __shfl_xor(li,32);
  float rinv = c1 / li;

  // stage out^T -> LDS (per-wave), then coalesced global write
  #pragma unroll
  for (int ni2=0; ni2<4; ++ni2){
    #pragma unroll
    for (int jh=0; jh<2; ++jh){
      float v0 = pacc[ni2][2*jh+0] * rinv;
      float v1 = pacc[ni2][2*jh+1] * rinv;
      *(u32*)&lds_o[w][lr][ni2*16 + lg*4 + 2*jh] = cvtpk(v0, v1);
    }
  }
  __syncthreads();
  int rr = l>>2, cc = (l&3)*16;
  u16x8 o0 = *(u16x8*)&lds_o[w][rr][cc];
  u16x8 o1 = *(u16x8*)&lds_o[w][rr][cc+8];
  size_t gaddr = ((size_t)(b*SS) + qw + rr)*512 + h*DD + cc;
  *(u16x8*)(outp + gaddr) = o0;
  *(u16x8*)(outp + gaddr + 8) = o1;
}

// ---------------- out = h(fp32) @ Wf2 + bf2 ----------------
__global__ __launch_bounds__(256) void k_ffn2(
    const float* __restrict__ hB, const float* __restrict__ Wf2,
    const float* __restrict__ bf2p, float* __restrict__ outp)
{
  int w = threadIdx.x >> 6, l = threadIdx.x & 63;
  int row = blockIdx.x*4 + w;
  const float* hr = hB + (size_t)row*EE + l*8;
  float s = 0.f;
  #pragma unroll
  for (int i=0;i<8;++i) s += hr[i] * Wf2[l*8+i];
  s = waveSum(s);
  if (l == 0) outp[row] = s + bf2p[0];
}

extern "C" void kernel_launch(void* const* d_in, const int* in_sizes, int n_in,
                              void* d_out, int out_size, void* d_ws, size_t ws_size,
                              hipStream_t stream)
{
  const int*   item_inputs = (const int*)d_in[0];
  const float* label_in    = (const float*)d_in[1];
  const int*   type_inputs = (const int*)d_in[2];
  const int*   item_ids    = (const int*)d_in[3];
  const float* rel         = (const float*)d_in[4];
  const float* tstamp      = (const float*)d_in[5];
  const float* qresp       = (const float*)d_in[6];
  const float* use_table   = (const float*)d_in[7];
  const float* type_table  = (const float*)d_in[8];
  const float* W_int       = (const float*)d_in[9];
  const float* b_int       = (const float*)d_in[10];
  const float* Wq          = (const float*)d_in[11];
  const float* bq          = (const float*)d_in[12];
  const float* Wk          = (const float*)d_in[13];
  const float* bk          = (const float*)d_in[14];
  const float* Wv          = (const float*)d_in[15];
  const float* bv          = (const float*)d_in[16];
  const float* Wf1         = (const float*)d_in[17];
  const float* bf1         = (const float*)d_in[18];
  const float* Wf2         = (const float*)d_in[19];
  const float* bf2         = (const float*)d_in[20];
  const float* l1p         = (const float*)d_in[21];
  const float* l2p         = (const float*)d_in[22];
  float* out = (float*)d_out;
  (void)in_sizes; (void)n_in; (void)out_size; (void)ws_size;

  char* p = (char*)d_ws;
  auto alloc = [&](size_t bytes)->char*{ char* r = p; p += (bytes + 255) & ~(size_t)255; return r; };
  const size_t NE  = (size_t)NROW*EE;
  const size_t NE2 = NE*2;
  ushort* xemb    = (ushort*)alloc(NE2);            // later reused as RB (flash out)
  ushort* inputsB = (ushort*)alloc(NE2);
  ushort* Mbuf    = (ushort*)alloc((size_t)BB*SS*SS*2);
  ushort* qB2     = (ushort*)alloc(2*NE2);          // later reused as hB (fp32)
  ushort* kvB     = (ushort*)alloc(2*NE2);          // kB | VtB adjacent
  ushort* OBcat   = (ushort*)alloc((size_t)NROW*1024*2);
  ushort* WtALL   = (ushort*)alloc((size_t)(7*262144 + 524288)*2);
  float*  T4f     = (float*)alloc(6*EE*4);          // T4 (4*512) | cs2 | cs3 contiguous
  float*  cs2f    = T4f + 4*EE;
  float*  cs3f    = T4f + 5*EE;
  ushort* kB   = kvB;
  ushort* VtB  = kvB + NE;
  ushort* RB   = xemb;          // alias: xemb dead after inputs-GEMM
  float*  hB   = (float*)qB2;   // alias: qB2 dead after flash1

  const int* nullI = nullptr;
  const float* nullF = nullptr;

  // prep
  transpose_all<<<dim3(16,32,8),256,0,stream>>>(W_int, Wq, Wk, Wv, Wf1, WtALL);
  k0_zero<<<6,512,0,stream>>>(T4f);
  k0_pre<<<dim3(6,8),512,0,stream>>>(type_table, W_int, T4f);
  k_gather<<<NROW/4,256,0,stream>>>(item_inputs, item_ids, use_table, xemb, OBcat);
  k3_M<<<NROW/4,256,0,stream>>>(rel, tstamp, l1p, l2p, Mbuf);

  // inputs = relu(item@W0 + T4[type] + qresp*cs2 + label*cs3 + b_int)
  gemm_bt<0,11,0><<<dim3(128,4,1),256,0,stream>>>(xemb,512,0, WtALL,0, inputsB,512,0, nullptr,
                                                  b_int, nullF, 512,
                                                  type_inputs, T4f, cs2f, cs3f, qresp, label_in);
  // Q projections, both layers (A = OBcat[:,512:])
  gemm_bt<1,1,0><<<dim3(128,4,2),256,0,stream>>>(OBcat+512,1024,0, WtALL+262144,262144,
                                                 qB2,0,NE, nullptr, bq, bq+EE, 512,
                                                 nullI,nullF,nullF,nullF,nullF,nullF);
  // layer 0 K,V
  gemm_bt<3,1,0><<<dim3(128,4,2),256,0,stream>>>(inputsB,512,0, WtALL+3*262144,262144,
                                                 kB,0,NE, nullptr, bk, bv, 512,
                                                 nullI,nullF,nullF,nullF,nullF,nullF);
  flash_attn<<<2048,256,0,stream>>>(qB2, kB, VtB, l1p, l2p, RB);
  // OBcat[:, :512] = MV0 + RB
  gemm_bt<0,32,1><<<512,256,0,stream>>>(Mbuf,512,(size_t)SS*SS, VtB,(size_t)EE*SS,
                                        OBcat,1024,(size_t)512*1024, RB,
                                        nullF, nullF, 512,
                                        nullI,nullF,nullF,nullF,nullF,nullF);
  // layer 1 K,V (from OBcat[:, :512])
  gemm_bt<3,1,0><<<dim3(128,4,2),256,0,stream>>>(OBcat,1024,0, WtALL+5*262144,262144,
                                                 kB,0,NE, nullptr, bk+EE, bv+EE, 512,
                                                 nullI,nullF,nullF,nullF,nullF,nullF);
  flash_attn<<<2048,256,0,stream>>>(qB2+NE, kB, VtB, l1p, l2p, RB);
  // OBcat[:, :512] += relu(MV1 + RB)
  gemm_bt<0,64,1><<<512,256,0,stream>>>(Mbuf,512,(size_t)SS*SS, VtB,(size_t)EE*SS,
                                        OBcat,1024,(size_t)512*1024, RB,
                                        nullF, nullF, 512,
                                        nullI,nullF,nullF,nullF,nullF,nullF);
  // final MLP: h = relu(OBcat@Wf1 + bf1) -> fp32
  gemm_bt<0,19,0><<<dim3(128,4,1),256,0,stream>>>(OBcat,1024,0, WtALL+7*262144,0,
                                                  (ushort*)hB,512,0, nullptr,
                                                  bf1, nullF, 1024,
                                                  nullI,nullF,nullF,nullF,nullF,nullF);
  k_ffn2<<<NROW/4,256,0,stream>>>(hB, Wf2, bf2, out);
}

// Round 8
// 476.214 us; speedup vs baseline: 1.5125x; 1.3694x over previous
//
#include <hip/hip_runtime.h>
#include <hip/hip_bf16.h>

#define BB 32
#define SS 512
#define EE 512
#define HH 8
#define DD 64
#define NROW (BB*SS)   // 16384

typedef unsigned short ushort;
typedef unsigned int u32;
typedef short bf16x8 __attribute__((ext_vector_type(8)));
typedef ushort u16x8 __attribute__((ext_vector_type(8)));
typedef float f32x4 __attribute__((ext_vector_type(4)));

__device__ __forceinline__ float bfu2f(ushort u){ return __uint_as_float(((u32)u)<<16); }
__device__ __forceinline__ ushort f2bfu(float f){
  __hip_bfloat16 h = __float2bfloat16(f);
  return *reinterpret_cast<ushort*>(&h);
}
__device__ __forceinline__ u32 cvtpk(float lo, float hi){
  u32 r; asm("v_cvt_pk_bf16_f32 %0, %1, %2" : "=v"(r) : "v"(lo), "v"(hi)); return r;
}
__device__ __forceinline__ float waveMax(float v){
  #pragma unroll
  for (int o = 32; o > 0; o >>= 1) v = fmaxf(v, __shfl_xor(v, o));
  return v;
}
__device__ __forceinline__ float waveSum(float v){
  #pragma unroll
  for (int o = 32; o > 0; o >>= 1) v += __shfl_xor(v, o);
  return v;
}
__device__ __forceinline__ void async_cp16(const ushort* g, ushort* l){
  __builtin_amdgcn_global_load_lds(
      (const __attribute__((address_space(1))) u32*)g,
      (__attribute__((address_space(3))) u32*)l, 16, 0, 0);
}

// ---------------- fused transpose of all weights: fp32 [K][N] -> bf16 [N][K] ----------------
__global__ __launch_bounds__(256) void transpose_all(
    const float* __restrict__ W_int, const float* __restrict__ Wq,
    const float* __restrict__ Wk, const float* __restrict__ Wv,
    const float* __restrict__ Wf1, ushort* __restrict__ WtALL)
{
  __shared__ float tile[32][33];
  int z = blockIdx.z;
  const float* src; int K; size_t dsto;
  switch(z){
    case 0: src=W_int;        K=512;  dsto=0;        break;
    case 1: src=Wq;           K=512;  dsto=262144;   break;
    case 2: src=Wq+262144;    K=512;  dsto=2*262144; break;
    case 3: src=Wk;           K=512;  dsto=3*262144; break;
    case 4: src=Wv;           K=512;  dsto=4*262144; break;
    case 5: src=Wk+262144;    K=512;  dsto=5*262144; break;
    case 6: src=Wv+262144;    K=512;  dsto=6*262144; break;
    default: src=Wf1;         K=1024; dsto=7*262144; break;
  }
  if ((int)blockIdx.y*32 >= K) return;
  ushort* out = WtALL + dsto;
  int lx = threadIdx.x & 31, ly = threadIdx.x >> 5;  // 32 x 8
  int n = blockIdx.x*32 + lx;
  #pragma unroll
  for (int r=0;r<32;r+=8){
    int k = blockIdx.y*32 + ly + r;
    tile[ly+r][lx] = src[(size_t)k*512 + n];
  }
  __syncthreads();
  int kk = blockIdx.y*32 + lx;
  #pragma unroll
  for (int r=0;r<32;r+=8){
    int nn = blockIdx.x*32 + ly + r;
    out[(size_t)nn*K + kk] = f2bfu(tile[lx][ly+r]);
  }
}

// ---------------- K0: zero then atomic partial-K accumulate ----------------
__global__ __launch_bounds__(512) void k0_zero(float* __restrict__ T4f){
  int i = blockIdx.x*512 + threadIdx.x;
  T4f[i] = 0.f;      // grid 6, covers 6*512 floats (T4 | cs2 | cs3)
}
__global__ __launch_bounds__(512) void k0_pre(const float* __restrict__ type_table,
                       const float* __restrict__ W_int, float* __restrict__ T4f)
{
  int e = threadIdx.x;
  int blk = blockIdx.x;          // 0..5
  int k0 = blockIdx.y * 64;      // 8 K-chunks
  float a = 0.f;
  if (blk < 4) {
    #pragma unroll 4
    for (int k = k0; k < k0+64; ++k)
      a += type_table[blk*EE + k] * W_int[(size_t)(EE + k)*EE + e];
  } else if (blk == 4) {
    #pragma unroll 4
    for (int k = k0; k < k0+64; ++k) a += W_int[(size_t)(2*EE + k)*EE + e];
  } else {
    #pragma unroll 4
    for (int k = k0; k < k0+64; ++k) a += W_int[(size_t)(3*EE + k)*EE + e];
  }
  atomicAdd(&T4f[blk*EE + e], a);
}

// ---------------- gathers: item emb -> xemb, query emb -> OBcat[:,512:] ----------------
__global__ __launch_bounds__(256) void k_gather(
    const int* __restrict__ item, const int* __restrict__ ids,
    const float* __restrict__ ut,
    ushort* __restrict__ xemb, ushort* __restrict__ obcat)
{
  int idx = blockIdx.x*256 + threadIdx.x;   // NROW*64 total
  int row = idx >> 6, c = (idx & 63)*8;
  int s = row & (SS-1);
  const float* isrc = ut + (size_t)item[row]*EE + c;
  const float* qsrc = ut + (size_t)ids[row]*EE + c;
  u16x8 xv, qv;
  #pragma unroll
  for (int i=0;i<8;++i){
    xv[i] = (s==0) ? (ushort)0 : f2bfu(isrc[i]);
    qv[i] = f2bfu(qsrc[i]);
  }
  *(u16x8*)(xemb + (size_t)row*EE + c) = xv;
  *(u16x8*)(obcat+ (size_t)row*1024 + 512 + c) = qv;
}

// ---------------- K3: M = (1-l1)*l2*softmax(tsc) + l1*softmax(rsc) -> bf16 ----------------
__global__ __launch_bounds__(256) void k3_M(
  const float* __restrict__ rel, const float* __restrict__ ts,
  const float* __restrict__ l1p, const float* __restrict__ l2p,
  ushort* __restrict__ Mout)
{
  int w = threadIdx.x >> 6, lane = threadIdx.x & 63;
  int row = blockIdx.x*4 + w;
  int q = row & (SS-1);
  const float* tr = ts + (size_t)row*SS;
  const float* rr = rel + (size_t)row*SS;
  float tv[8], rv[8];
  float m1 = -INFINITY, m2 = -1e10f;
  #pragma unroll
  for (int j=0;j<8;++j){
    int k = lane + 64*j;
    float t = tr[k];
    tv[j] = (k <= q) ? __expf(-fabsf(t)) : -INFINITY;
    m1 = fmaxf(m1, tv[j]);
    float rvv = (k > q) ? rr[k] : 0.f;
    rv[j] = (rvv == 0.f) ? -10000.f : rvv;
    m2 = fmaxf(m2, rv[j]);
  }
  m1 = waveMax(m1); m2 = waveMax(m2);
  float s1=0.f, s2=0.f;
  float p1[8], p2[8];
  #pragma unroll
  for (int j=0;j<8;++j){
    p1[j] = __expf(tv[j]-m1); s1 += p1[j];
    p2[j] = __expf(rv[j]-m2); s2 += p2[j];
  }
  s1 = waveSum(s1); s2 = waveSum(s2);
  float l1v = l1p[0], l2v = l2p[0];
  float i1 = (1.f-l1v)*l2v/s1, i2 = l1v/s2;
  ushort* Mr = Mout + (size_t)row*SS;
  #pragma unroll
  for (int j=0;j<8;++j)
    Mr[lane+64*j] = f2bfu(p1[j]*i1 + p2[j]*i2);
}

// ---------------- MFMA GEMM, 2-phase dbuf pipeline ----------------
// MODE 0: C[row*ldc+col]; MODE 1: [b,h,s,d]; MODE 3: z==0 -> [b,h,s,d], z==1 -> Vt[b][e][s]
// FLAGS: 1=bias, 2=relu, 8=k1 epilogue, 16=f32-out, 32=MV compose (C=v+RB), 64=MV compose+relu-add
// GRID: 0 = (x,y,z) grid; 1 = flat XCD-swizzled (512 blocks, 4x4 tiles x 32 batches)
template<int MODE, int FLAGS, int GRID>
__global__ __launch_bounds__(256) void gemm_bt(
    const ushort* __restrict__ A, int lda, size_t sA,
    const ushort* __restrict__ Bt, size_t sB,
    ushort* __restrict__ C, int ldc, size_t sC,
    const ushort* __restrict__ RBp,
    const float* __restrict__ bias0, const float* __restrict__ bias1, int K,
    const int* __restrict__ typeIdx, const float* __restrict__ T4f,
    const float* __restrict__ cs2, const float* __restrict__ cs3,
    const float* __restrict__ qresp, const float* __restrict__ label)
{
  __shared__ ushort As[2][128*32];
  __shared__ ushort Bs[2][128*32];
  int bx, by, z;
  if constexpr (GRID == 0){ bx = blockIdx.x; by = blockIdx.y; z = blockIdx.z; }
  else {
    int wg = blockIdx.x;
    int xcd = wg & 7, t2 = wg >> 3;
    z = (xcd << 2) | (t2 >> 4);        // 4 batches per XCD -> M[b],Vt[b] L2-resident
    int tile = t2 & 15;
    bx = tile & 3; by = tile >> 2;
  }
  int t = threadIdx.x;
  int w = t >> 6, l = t & 63;
  int row0 = bx * 128;
  int n0 = by * 128;
  const ushort* Ab = A + (size_t)z*sA;
  const ushort* Bb = Bt + (size_t)z*sB;
  ushort* Cb = C + (size_t)z*sC;
  const float* bias = (z == 0) ? bias0 : bias1;

  f32x4 acc[4][4];
  f32x4 zero4 = {0.f,0.f,0.f,0.f};
  #pragma unroll
  for (int i=0;i<4;++i)
    #pragma unroll
    for (int j=0;j<4;++j) acc[i][j] = zero4;

  int wr = w >> 1, wc = w & 1;
  int lr = l & 15, lg = l >> 4;
  int arow = wr*64 + lr;
  int brow = wc*64 + lr;
  int kgrp = lg*8;

  auto STAGE = [&](int buf, int k0){
    #pragma unroll
    for (int j=0;j<2;++j){
      int off = (j*256 + t)*8;           // ushort offset within 128x32 tile
      int r = off >> 5, kc = off & 31;
      async_cp16(Ab + (size_t)(row0 + r)*lda + k0 + kc, &As[buf][off]);
      async_cp16(Bb + (size_t)(n0  + r)*K   + k0 + kc, &Bs[buf][off]);
    }
  };

  STAGE(0, 0);
  asm volatile("s_waitcnt vmcnt(0)" ::: "memory");
  __syncthreads();
  int cur = 0;
  for (int k0 = 0; k0 < K; k0 += 32) {
    if (k0 + 32 < K) STAGE(cur^1, k0+32);   // prefetch overlaps MFMA below
    bf16x8 af[4], bfr[4];
    #pragma unroll
    for (int i=0;i<4;++i){
      af[i]  = *(const bf16x8*)(&As[cur][(arow + i*16)*32 + kgrp]);
      bfr[i] = *(const bf16x8*)(&Bs[cur][(brow + i*16)*32 + kgrp]);
    }
    #pragma unroll
    for (int i=0;i<4;++i)
      #pragma unroll
      for (int j=0;j<4;++j)
        acc[i][j] = __builtin_amdgcn_mfma_f32_16x16x32_bf16(af[i], bfr[j], acc[i][j], 0,0,0);
    asm volatile("s_waitcnt vmcnt(0)" ::: "memory");
    __syncthreads();
    cur ^= 1;
  }

  int crow0 = row0 + wr*64 + lg*4;
  int ccol0 = n0 + wc*64 + lr;
  #pragma unroll
  for (int mi=0;mi<4;++mi){
    #pragma unroll
    for (int ni=0;ni<4;++ni){
      int col = ccol0 + ni*16;
      float bv = 0.f;
      if constexpr ((FLAGS & 1) != 0) bv = bias[col];
      #pragma unroll
      for (int j=0;j<4;++j){
        int row = crow0 + mi*16 + j;
        float v = acc[mi][ni][j] + bv;
        if constexpr ((FLAGS & 8) != 0) {
          int tt = typeIdx[row];
          v += T4f[tt*EE + col] + qresp[row]*cs2[col] + label[row]*cs3[col];
        }
        if constexpr ((FLAGS & 2) != 0) v = fmaxf(v, 0.f);
        if constexpr ((FLAGS & (32|64)) != 0)
          v += bfu2f(RBp[(size_t)z*262144 + row*512 + col]);   // + flash output
        size_t idx;
        if constexpr (MODE == 0)      idx = (size_t)row*ldc + col;
        else if constexpr (MODE == 1) idx = ((size_t)(row>>9)*HH + (col>>6))*(SS*DD) + (size_t)(row&(SS-1))*DD + (col&63);
        else {
          if (z == 0) idx = ((size_t)(row>>9)*HH + (col>>6))*(SS*DD) + (size_t)(row&(SS-1))*DD + (col&63);
          else        idx = (size_t)(row>>9)*(EE*SS) + (size_t)col*SS + (row&(SS-1));
        }
        if constexpr ((FLAGS & 16) != 0) ((float*)Cb)[idx] = v;
        else if constexpr ((FLAGS & 64) != 0) {
          float old = bfu2f(Cb[idx]);
          Cb[idx] = f2bfu(old + fmaxf(v, 0.f));
        } else Cb[idx] = f2bfu(v);
      }
    }
  }
}

// ---------------- flash attention: out = c1*softmax(QK^T/8)@V (causal) ----------------
// LDS-staged K/V tiles (64 kv), XOR-swizzled, double-buffered; swapped mfma(K,Q);
// register P; online max; paired q-tiles (qt, 7-qt) for uniform work; XCD-swizzled grid.
// qb,kb: [b,h,s,d]; vt: [b][e][s]; outp: RB row-major ld 512
__global__ __launch_bounds__(256) void flash_attn(
    const ushort* __restrict__ qb, const ushort* __restrict__ kb,
    const ushort* __restrict__ vt,
    const float* __restrict__ l1p, const float* __restrict__ l2p,
    ushort* __restrict__ outp)
{
  __shared__ ushort smem[16384];       // 32KB: [buf][K 8KB | V^T 8KB]
  int wg = blockIdx.x;                 // 1024 blocks
  int xcd = wg & 7, idx = wg >> 3;
  int bh = (xcd << 5) | (idx & 31);    // 32 heads per XCD -> K/V L2-resident
  int pr = idx >> 5;                   // q-tile pair id 0..3 -> tiles (pr, 7-pr)
  const int b = bh>>3, h = bh&7;
  const int t = threadIdx.x, w = t>>6, l = t&63;
  const int lr = l&15, lg = l>>4;
  const float c1 = (1.f - l1p[0])*(1.f - l2p[0]);
  const float C1 = 0.125f * 1.44269504f;

  const char* kg = (const char*)(kb + (size_t)bh*SS*DD);
  const char* vg = (const char*)(vt + ((size_t)b*EE + h*DD)*SS);

  // per-lane swizzled read offsets (bytes). f(row) = (row&3)|((row>>3&1)<<2)
  const int fK = (lr&3)|(((lr>>2)&1)<<2);   // = f(krow) for all ni
  const int fV = (lr&3)|(((lr>>3)&1)<<2);   // = f(vrow) for all ni2
  const int prow = ((lr>>2)<<3)|(lr&3);
  int ko[4], vo[4];
  #pragma unroll
  for (int ni=0;ni<4;++ni)
    ko[ni] = (prow + (ni&1)*4 + (ni>>1)*32)*128 + ((lg*16) ^ (fK<<4));
  #pragma unroll
  for (int ni=0;ni<4;++ni)
    vo[ni] = lr*128 + ni*2048 + 8192 + ((lg*16) ^ (fV<<4));

  auto STAGE = [&](int buf, int kt){
    #pragma unroll
    for (int s2=0;s2<2;++s2){
      int o = s2*4096 + t*16;          // byte offset within 8KB tile (LDS linear)
      int row = o>>7;
      int f = (row&3)|(((row>>3)&1)<<2);
      int col = (o&127) ^ (f<<4);      // inverse-swizzled global column
      async_cp16((const ushort*)(kg + (size_t)kt*8192 + row*128 + col),
                 smem + buf*8192 + o/2);
      async_cp16((const ushort*)(vg + (size_t)row*1024 + (size_t)kt*128 + col),
                 smem + buf*8192 + 4096 + o/2);
    }
  };

  auto process = [&](int qs){
    const int qw = qs*64 + w*16;
    const ushort* qrow = qb + ((size_t)bh*SS + qw + lr)*DD;
    bf16x8 qa0 = *(const bf16x8*)(qrow + lg*8);
    bf16x8 qa1 = *(const bf16x8*)(qrow + 32 + lg*8);

    f32x4 pacc[4];
    f32x4 zero4 = {0.f,0.f,0.f,0.f};
    #pragma unroll
    for (int i=0;i<4;++i) pacc[i]=zero4;
    float li = 0.f, mx = -1e30f;

    __syncthreads();                   // protect smem from previous subtile epilogue
    STAGE(0, 0);
    asm volatile("s_waitcnt vmcnt(0)" ::: "memory");
    __syncthreads();
    int buf = 0;
    for (int kt=0; kt<=qs; ++kt){
      if (kt < qs) STAGE(buf^1, kt+1);     // prefetch overlaps compute below
      const char* kls = (const char*)smem + buf*16384;
      f32x4 sc[4];
      #pragma unroll
      for (int i=0;i<4;++i) sc[i]=zero4;
      #pragma unroll
      for (int ni=0;ni<4;++ni){
        bf16x8 kf0 = *(const bf16x8*)(kls + ko[ni]);
        bf16x8 kf1 = *(const bf16x8*)(kls + (ko[ni]^64));
        sc[ni] = __builtin_amdgcn_mfma_f32_16x16x32_bf16(kf0, qa0, sc[ni], 0,0,0);
        sc[ni] = __builtin_amdgcn_mfma_f32_16x16x32_bf16(kf1, qa1, sc[ni], 0,0,0);
      }
      if (kt == qs){                   // diagonal tile: mask k > q
        int q = qw + lr;
        #pragma unroll
        for (int ni=0;ni<4;++ni){
          int kb0 = kt*64 + (ni>>1)*32 + (ni&1)*4 + lg*8;
          #pragma unroll
          for (int j=0;j<4;++j)
            sc[ni][j] = (kb0 + j > q) ? -1e30f : sc[ni][j];
        }
      }
      // online max (per q-row = this lane's lr; reduce over lg groups)
      float tm = -1e30f;
      #pragma unroll
      for (int ni=0;ni<4;++ni)
        #pragma unroll
        for (int j=0;j<4;++j) tm = fmaxf(tm, sc[ni][j]);
      tm = fmaxf(tm, __shfl_xor(tm,16));
      tm = fmaxf(tm, __shfl_xor(tm,32));
      float nm = fmaxf(mx, tm);
      float corr = __builtin_exp2f((mx-nm)*C1);
      mx = nm;
      float mcc = nm*C1;
      float tsum = 0.f;
      u32 pk[4][2];
      #pragma unroll
      for (int ni=0;ni<4;++ni){
        float p0 = __builtin_exp2f(fmaf(sc[ni][0], C1, -mcc));
        float p1 = __builtin_exp2f(fmaf(sc[ni][1], C1, -mcc));
        float p2 = __builtin_exp2f(fmaf(sc[ni][2], C1, -mcc));
        float p3 = __builtin_exp2f(fmaf(sc[ni][3], C1, -mcc));
        tsum += (p0+p1)+(p2+p3);
        pk[ni][0] = cvtpk(p0,p1);
        pk[ni][1] = cvtpk(p2,p3);
      }
      li = li*corr + tsum;
      #pragma unroll
      for (int i=0;i<4;++i) pacc[i] *= corr;
      // PV from swizzled V^T tile
      #pragma unroll
      for (int kh=0;kh<2;++kh){
        union { u32 u[4]; bf16x8 v; } pu;
        pu.u[0]=pk[2*kh][0]; pu.u[1]=pk[2*kh][1];
        pu.u[2]=pk[2*kh+1][0]; pu.u[3]=pk[2*kh+1][1];
        bf16x8 pa = pu.v;
        #pragma unroll
        for (int ni2=0;ni2<4;++ni2){
          bf16x8 vf = *(const bf16x8*)(kls + (vo[ni2]^(kh*64)));
          pacc[ni2] = __builtin_amdgcn_mfma_f32_16x16x32_bf16(vf, pa, pacc[ni2], 0,0,0);
        }
      }
      asm volatile("s_waitcnt vmcnt(0)" ::: "memory");
      __syncthreads();
      buf ^= 1;
    }
    li += __shfl_xor(li,16);
    li += __shfl_xor(li,32);
    float rinv = c1/li;

    // stage out^T -> LDS (aliases staging buffers; loop-end barrier makes this safe)
    ushort (*lds_o)[16][72] = (ushort(*)[16][72])smem;
    #pragma unroll
    for (int ni2=0;ni2<4;++ni2){
      #pragma unroll
      for (int jh=0;jh<2;++jh){
        float v0 = pacc[ni2][2*jh+0]*rinv;
        float v1 = pacc[ni2][2*jh+1]*rinv;
        *(u32*)&lds_o[w][lr][ni2*16 + lg*4 + 2*jh] = cvtpk(v0,v1);
      }
    }
    __syncthreads();
    int rr = l>>2, cc = (l&3)*16;
    u16x8 o0 = *(u16x8*)&lds_o[w][rr][cc];
    u16x8 o1 = *(u16x8*)&lds_o[w][rr][cc+8];
    size_t gaddr = ((size_t)(b*SS) + qw + rr)*512 + h*DD + cc;
    *(u16x8*)(outp + gaddr) = o0;
    *(u16x8*)(outp + gaddr + 8) = o1;
  };

  process(pr);
  process(7-pr);
}

// ---------------- out = h(fp32) @ Wf2 + bf2 ----------------
__global__ __launch_bounds__(256) void k_ffn2(
    const float* __restrict__ hB, const float* __restrict__ Wf2,
    const float* __restrict__ bf2p, float* __restrict__ outp)
{
  int w = threadIdx.x >> 6, l = threadIdx.x & 63;
  int row = blockIdx.x*4 + w;
  const float* hr = hB + (size_t)row*EE + l*8;
  float s = 0.f;
  #pragma unroll
  for (int i=0;i<8;++i) s += hr[i] * Wf2[l*8+i];
  s = waveSum(s);
  if (l == 0) outp[row] = s + bf2p[0];
}

extern "C" void kernel_launch(void* const* d_in, const int* in_sizes, int n_in,
                              void* d_out, int out_size, void* d_ws, size_t ws_size,
                              hipStream_t stream)
{
  const int*   item_inputs = (const int*)d_in[0];
  const float* label_in    = (const float*)d_in[1];
  const int*   type_inputs = (const int*)d_in[2];
  const int*   item_ids    = (const int*)d_in[3];
  const float* rel         = (const float*)d_in[4];
  const float* tstamp      = (const float*)d_in[5];
  const float* qresp       = (const float*)d_in[6];
  const float* use_table   = (const float*)d_in[7];
  const float* type_table  = (const float*)d_in[8];
  const float* W_int       = (const float*)d_in[9];
  const float* b_int       = (const float*)d_in[10];
  const float* Wq          = (const float*)d_in[11];
  const float* bq          = (const float*)d_in[12];
  const float* Wk          = (const float*)d_in[13];
  const float* bk          = (const float*)d_in[14];
  const float* Wv          = (const float*)d_in[15];
  const float* bv          = (const float*)d_in[16];
  const float* Wf1         = (const float*)d_in[17];
  const float* bf1         = (const float*)d_in[18];
  const float* Wf2         = (const float*)d_in[19];
  const float* bf2         = (const float*)d_in[20];
  const float* l1p         = (const float*)d_in[21];
  const float* l2p         = (const float*)d_in[22];
  float* out = (float*)d_out;
  (void)in_sizes; (void)n_in; (void)out_size; (void)ws_size;

  char* p = (char*)d_ws;
  auto alloc = [&](size_t bytes)->char*{ char* r = p; p += (bytes + 255) & ~(size_t)255; return r; };
  const size_t NE  = (size_t)NROW*EE;
  const size_t NE2 = NE*2;
  ushort* xemb    = (ushort*)alloc(NE2);            // later reused as RB (flash out)
  ushort* inputsB = (ushort*)alloc(NE2);
  ushort* Mbuf    = (ushort*)alloc((size_t)BB*SS*SS*2);
  ushort* qB2     = (ushort*)alloc(2*NE2);          // later reused as hB (fp32)
  ushort* kvB     = (ushort*)alloc(2*NE2);          // kB | VtB adjacent
  ushort* OBcat   = (ushort*)alloc((size_t)NROW*1024*2);
  ushort* WtALL   = (ushort*)alloc((size_t)(7*262144 + 524288)*2);
  float*  T4f     = (float*)alloc(6*EE*4);          // T4 (4*512) | cs2 | cs3 contiguous
  float*  cs2f    = T4f + 4*EE;
  float*  cs3f    = T4f + 5*EE;
  ushort* kB   = kvB;
  ushort* VtB  = kvB + NE;
  ushort* RB   = xemb;          // alias: xemb dead after inputs-GEMM
  float*  hB   = (float*)qB2;   // alias: qB2 dead after flash1

  const int* nullI = nullptr;
  const float* nullF = nullptr;

  // prep
  transpose_all<<<dim3(16,32,8),256,0,stream>>>(W_int, Wq, Wk, Wv, Wf1, WtALL);
  k0_zero<<<6,512,0,stream>>>(T4f);
  k0_pre<<<dim3(6,8),512,0,stream>>>(type_table, W_int, T4f);
  k_gather<<<NROW/4,256,0,stream>>>(item_inputs, item_ids, use_table, xemb, OBcat);
  k3_M<<<NROW/4,256,0,stream>>>(rel, tstamp, l1p, l2p, Mbuf);

  // inputs = relu(item@W0 + T4[type] + qresp*cs2 + label*cs3 + b_int)
  gemm_bt<0,11,0><<<dim3(128,4,1),256,0,stream>>>(xemb,512,0, WtALL,0, inputsB,512,0, nullptr,
                                                  b_int, nullF, 512,
                                                  type_inputs, T4f, cs2f, cs3f, qresp, label_in);
  // Q projections, both layers (A = OBcat[:,512:])
  gemm_bt<1,1,0><<<dim3(128,4,2),256,0,stream>>>(OBcat+512,1024,0, WtALL+262144,262144,
                                                 qB2,0,NE, nullptr, bq, bq+EE, 512,
                                                 nullI,nullF,nullF,nullF,nullF,nullF);
  // layer 0 K,V
  gemm_bt<3,1,0><<<dim3(128,4,2),256,0,stream>>>(inputsB,512,0, WtALL+3*262144,262144,
                                                 kB,0,NE, nullptr, bk, bv, 512,
                                                 nullI,nullF,nullF,nullF,nullF,nullF);
  flash_attn<<<1024,256,0,stream>>>(qB2, kB, VtB, l1p, l2p, RB);
  // OBcat[:, :512] = MV0 + RB
  gemm_bt<0,32,1><<<512,256,0,stream>>>(Mbuf,512,(size_t)SS*SS, VtB,(size_t)EE*SS,
                                        OBcat,1024,(size_t)512*1024, RB,
                                        nullF, nullF, 512,
                                        nullI,nullF,nullF,nullF,nullF,nullF);
  // layer 1 K,V (from OBcat[:, :512])
  gemm_bt<3,1,0><<<dim3(128,4,2),256,0,stream>>>(OBcat,1024,0, WtALL+5*262144,262144,
                                                 kB,0,NE, nullptr, bk+EE, bv+EE, 512,
                                                 nullI,nullF,nullF,nullF,nullF,nullF);
  flash_attn<<<1024,256,0,stream>>>(qB2+NE, kB, VtB, l1p, l2p, RB);
  // OBcat[:, :512] += relu(MV1 + RB)
  gemm_bt<0,64,1><<<512,256,0,stream>>>(Mbuf,512,(size_t)SS*SS, VtB,(size_t)EE*SS,
                                        OBcat,1024,(size_t)512*1024, RB,
                                        nullF, nullF, 512,
                                        nullI,nullF,nullF,nullF,nullF,nullF);
  // final MLP: h = relu(OBcat@Wf1 + bf1) -> fp32
  gemm_bt<0,19,0><<<dim3(128,4,1),256,0,stream>>>(OBcat,1024,0, WtALL+7*262144,0,
                                                  (ushort*)hB,512,0, nullptr,
                                                  bf1, nullF, 1024,
                                                  nullI,nullF,nullF,nullF,nullF,nullF);
  k_ffn2<<<NROW/4,256,0,stream>>>(hB, Wf2, bf2, out);
}